// Round 9
// baseline (427.682 us; speedup 1.0000x reference)
//
#include <hip/hip_runtime.h>
#include <hip/hip_bf16.h>
#include <cstdint>
#include <cstddef>

// SGM fused pipeline, MI355X gfx950.
// Shapes: B=32 L=64 N=1024 D=512 C=8192 WS=3 NH=16 HD=32 HID=1024
// Encoder rows M=12288 (side*6144 + pos*3 + w), cross rows 4096 (side*2048+pos).

typedef __attribute__((ext_vector_type(8))) short s16x8;
typedef __attribute__((ext_vector_type(8))) unsigned short u16x8;
typedef __attribute__((ext_vector_type(4))) unsigned short u16x4;
typedef __attribute__((ext_vector_type(4))) float f32x4;

__device__ __forceinline__ float b2f(unsigned short u) {
  union { unsigned int i; float f; } c; c.i = ((unsigned int)u) << 16; return c.f;
}
__device__ __forceinline__ unsigned short f2b(float f) {
  union { float f; unsigned int i; } c; c.f = f;
  unsigned int x = c.i;
  return (unsigned short)((x + 0x7FFFu + ((x >> 16) & 1u)) >> 16); // RNE, no NaN in this net
}

// async global->LDS, 16B per lane; LDS dest is wave-uniform base + lane*16
#define GLOAD16(gp, lp)                                                        \
  __builtin_amdgcn_global_load_lds(                                           \
      (const __attribute__((address_space(1))) void*)(gp),                    \
      (__attribute__((address_space(3))) void*)(lp), 16, 0, 0)

// ---------------- fp32 -> bf16 convert (weights) ----------------
__global__ void cvt_f32_bf16(const float* __restrict__ s, unsigned short* __restrict__ d, int n4) {
  int i = blockIdx.x * 256 + threadIdx.x;
  if (i >= n4) return;
  float4 v = ((const float4*)s)[i];
  u16x4 o; o[0] = f2b(v.x); o[1] = f2b(v.y); o[2] = f2b(v.z); o[3] = f2b(v.w);
  *(u16x4*)(d + (size_t)i * 4) = o;
}

// ---------------- embedding + token add ----------------
__global__ void embed_k(const int* __restrict__ targets, const int* __restrict__ pad_p,
                        const float* __restrict__ ce, const float* __restrict__ ltok,
                        const float* __restrict__ rtok, float* __restrict__ x) {
  int idx = blockIdx.x * 256 + threadIdx.x;   // float4 index, 12288*128 total
  if (idx >= 12288 * 128) return;
  int row = idx >> 7, d4 = idx & 127;
  int side = row >= 6144;
  int rem = row - side * 6144;
  int pos = rem / 3, w = rem - pos * 3;
  int b = pos >> 6, l = pos & 63;
  int id;
  if (!side) { int ti = l + w - 3; id = (ti >= 0) ? targets[(b << 6) + ti] : *pad_p; }
  else       { int ti = l + w + 1; id = (ti < 64) ? targets[(b << 6) + ti] : *pad_p; }
  float4 cv = ((const float4*)ce)[(size_t)id * 128 + d4];
  float4 tv = ((const float4*)(side ? rtok : ltok))[d4];
  float4 o; o.x = cv.x + tv.x; o.y = cv.y + tv.y; o.z = cv.z + tv.z; o.w = cv.w + tv.w;
  ((float4*)x)[idx] = o;
}

// ---------------- LayerNorm (D=512, fp32 in -> bf16 out), one wave per row ----------------
__global__ __launch_bounds__(256) void ln_rows(const float* __restrict__ in,
    const float* __restrict__ g, const float* __restrict__ b,
    unsigned short* __restrict__ out, int M) {
  int row = blockIdx.x * 4 + (threadIdx.x >> 6);
  int lane = threadIdx.x & 63;
  const float* rp = in + (size_t)row * 512;
  float4 v0 = ((const float4*)rp)[lane * 2];
  float4 v1 = ((const float4*)rp)[lane * 2 + 1];
  float vv[8] = {v0.x, v0.y, v0.z, v0.w, v1.x, v1.y, v1.z, v1.w};
  float s = 0.f, ss = 0.f;
#pragma unroll
  for (int j = 0; j < 8; ++j) { s += vv[j]; ss += vv[j] * vv[j]; }
#pragma unroll
  for (int o = 1; o < 64; o <<= 1) { s += __shfl_xor(s, o); ss += __shfl_xor(ss, o); }
  float mean = s * (1.0f / 512.0f);
  float var = ss * (1.0f / 512.0f) - mean * mean;
  float inv = rsqrtf(var + 1e-5f);
  int c = lane * 8;
  u16x8 o8;
#pragma unroll
  for (int j = 0; j < 8; ++j) o8[j] = f2b((vv[j] - mean) * inv * g[c + j] + b[c + j]);
  *(u16x8*)(out + (size_t)row * 512 + c) = o8;
}

// ---------------- bf16 MFMA GEMM, 128x128, BK=64, counted-vmcnt 2-phase (T4) ----------------
// Per iter: STAGE(next buf, 8 loads) -> s_waitcnt vmcnt(8) (prev iter's loads done,
// new 8 stay in flight across this iter's MFMA) -> s_barrier (publish) -> ds_read +
// MFMA both 32-halves -> lgkmcnt(0) -> s_barrier (retire reads). No vmcnt(0) drain in
// steady state. Row-pair XOR swizzle (conflict-free, verified); swapped-operand MFMA
// -> float4/u16x4 wide epilogue stores; adaptive block order (row-fastest when
// nbx>=nby) for per-XCD L2 working set; bijective XCD swizzle.
// KVT=1: writes K to Kp[b][h][n][32] (u16x4) and V^T to VpT[b][h][d][n].
template<int RES, int GELU, int OUTBF, int KVT>
__global__ __launch_bounds__(256) void gemm128(
    const unsigned short* __restrict__ A, const unsigned short* __restrict__ Bt,
    const float* __restrict__ bias, const float* __restrict__ res,
    void* __restrict__ outp, int M, int N, int K) {
  __shared__ unsigned short sA[2][8192];   // [buf][half*4096 + 128rows x 32cols swz]
  __shared__ unsigned short sB[2][8192];
  const int tid = threadIdx.x;
  const int nbx = gridDim.x, nby = gridDim.y;
  int id = blockIdx.y * nbx + blockIdx.x;
  {
    const int nwg = nbx * nby;
    if ((nwg & 7) == 0) id = (id & 7) * (nwg >> 3) + (id >> 3);
  }
  int bm, bn;
  if (nbx >= nby) { bm = (id % nby) * 128; bn = (id / nby) * 128; }   // row-fastest
  else            { bm = (id / nbx) * 128; bn = (id % nbx) * 128; }   // col-fastest
  const int wave = tid >> 6, lane = tid & 63;
  const int wr = (wave >> 1) * 64, wc = (wave & 1) * 64;
  const int lrow = lane & 15, g = lane >> 4;
  f32x4 acc[4][4] = {};
  // read-side swizzled offset within a half: rowpair slot = ((row&1)*4|g) ^ ((row>>1)&7)
  const int xoff = (((((lrow & 1) << 2) | g) ^ ((lrow >> 1) & 7)) << 3);
  const int baseA = ((wr >> 1) + (lrow >> 1)) * 64 + xoff;
  const int baseB = ((wc >> 1) + (lrow >> 1)) * 64 + xoff;
  // stage-side pre-swizzled global (row, chunk) per lane (verified layout, conflicts=0)
  const int slot8 = (tid & 7) ^ ((tid >> 3) & 7);
  const int srow = ((tid >> 3) << 1) + (slot8 >> 2);   // + i*64
  const int scol = (slot8 & 3) << 3;
  const unsigned short* gA = A + (size_t)(bm + srow) * K + scol;
  const unsigned short* gB = Bt + (size_t)(bn + srow) * K + scol;
  const int NT = K >> 6;

#define STAGE128(buf, kt)                                                      \
  { _Pragma("unroll")                                                          \
    for (int h = 0; h < 2; ++h) {                                              \
      _Pragma("unroll")                                                        \
      for (int i = 0; i < 2; ++i) {                                            \
        GLOAD16(gA + (size_t)(i * 64) * K + (kt) * 64 + h * 32,                \
                &sA[buf][h * 4096 + i * 2048 + wave * 512]);                   \
        GLOAD16(gB + (size_t)(i * 64) * K + (kt) * 64 + h * 32,                \
                &sB[buf][h * 4096 + i * 2048 + wave * 512]);                   \
      }                                                                        \
    } }

  STAGE128(0, 0);          // 8 loads in flight
  int cur = 0;
  for (int kt = 0; kt < NT; ++kt) {
    if (kt + 1 < NT) {
      STAGE128(cur ^ 1, kt + 1);                       // +8 loads (16 outstanding)
      asm volatile("s_waitcnt vmcnt(8)" ::: "memory"); // oldest 8 (cur) retired
    } else {
      asm volatile("s_waitcnt vmcnt(0)" ::: "memory"); // tail drain
    }
    __builtin_amdgcn_s_barrier();                      // publish buffer cur
    asm volatile("" ::: "memory");
    // half 0
    s16x8 a0[4], b0[4];
#pragma unroll
    for (int m = 0; m < 4; ++m) a0[m] = *(const s16x8*)&sA[cur][baseA + m * 512];
#pragma unroll
    for (int n = 0; n < 4; ++n) b0[n] = *(const s16x8*)&sB[cur][baseB + n * 512];
    __builtin_amdgcn_s_setprio(1);
#pragma unroll
    for (int m = 0; m < 4; ++m)
#pragma unroll
      for (int n = 0; n < 4; ++n)
        acc[m][n] = __builtin_amdgcn_mfma_f32_16x16x32_bf16(b0[n], a0[m], acc[m][n], 0, 0, 0);
    __builtin_amdgcn_s_setprio(0);
    // half 1
    s16x8 a1[4], b1[4];
#pragma unroll
    for (int m = 0; m < 4; ++m) a1[m] = *(const s16x8*)&sA[cur][4096 + baseA + m * 512];
#pragma unroll
    for (int n = 0; n < 4; ++n) b1[n] = *(const s16x8*)&sB[cur][4096 + baseB + n * 512];
    __builtin_amdgcn_s_setprio(1);
#pragma unroll
    for (int m = 0; m < 4; ++m)
#pragma unroll
      for (int n = 0; n < 4; ++n)
        acc[m][n] = __builtin_amdgcn_mfma_f32_16x16x32_bf16(b1[n], a1[m], acc[m][n], 0, 0, 0);
    __builtin_amdgcn_s_setprio(0);
    asm volatile("s_waitcnt lgkmcnt(0)" ::: "memory"); // reads of cur sampled
    __builtin_amdgcn_s_barrier();                      // retire: cur may be overwritten
    cur ^= 1;
  }
#undef STAGE128

  // Swapped-operand C layout: lane -> row = bm+wr+m*16+lrow, cols = bn+wc+n*16+g*4+[0..3]
  const int orow_ = bm + wr + lrow;
  const int ocol_ = bn + wc + g * 4;
#pragma unroll
  for (int m = 0; m < 4; ++m) {
    const int row = orow_ + m * 16;
#pragma unroll
    for (int n = 0; n < 4; ++n) {
      const int col = ocol_ + n * 16;
      f32x4 v = acc[m][n];
      f32x4 b4 = *(const f32x4*)(bias + col);
      v += b4;
      if (GELU) {
#pragma unroll
        for (int r = 0; r < 4; ++r)
          v[r] = 0.5f * v[r] * (1.0f + erff(v[r] * 0.70710678118654752f));
      }
      if (RES) v += *(const f32x4*)(res + (size_t)row * N + col);
      if (KVT) {
        // row = b*1024 + n_vis ; col<512 -> K head block (contig dd), col>=512 -> V^T
        int bb = row >> 10, nn = row & 1023;
        unsigned short* Kp = (unsigned short*)outp;
        unsigned short* VpT = Kp + 16777216u;
        if (col < 512) {
          int hh = col >> 5, dd = col & 31;
          u16x4 o4;
#pragma unroll
          for (int r = 0; r < 4; ++r) o4[r] = f2b(v[r]);
          *(u16x4*)(Kp + (((size_t)(bb * 16 + hh)) * 1024 + nn) * 32 + dd) = o4;
        } else {
          int cc = col - 512, hh = cc >> 5, dd = cc & 31;
#pragma unroll
          for (int r = 0; r < 4; ++r)
            VpT[(((size_t)(bb * 16 + hh)) * 32 + dd + r) * 1024 + nn] = f2b(v[r]);
        }
      } else if (OUTBF) {
        u16x4 o4;
#pragma unroll
        for (int r = 0; r < 4; ++r) o4[r] = f2b(v[r]);
        *(u16x4*)((unsigned short*)outp + (size_t)row * N + col) = o4;
      } else {
        *(f32x4*)((float*)outp + (size_t)row * N + col) = v;
      }
    }
  }
}

// ---------------- windowed (WS=3) attention, thread per (side-pos, head, q-row) ----------------
__global__ __launch_bounds__(256) void winattn(const unsigned short* __restrict__ qkv,
                                               unsigned short* __restrict__ o) {
  int g = blockIdx.x * 256 + threadIdx.x;
  if (g >= 4096 * 48) return;
  int i = g % 3;
  int t = g / 3;
  int h = t & 15;
  int sp = t >> 4;
  const unsigned short* base = qkv + (size_t)sp * 4608 + h * 32;
  float qv[32];
  {
    const u16x8* qp = (const u16x8*)(base + (size_t)i * 1536);
#pragma unroll
    for (int c = 0; c < 4; ++c) {
      u16x8 v = qp[c];
#pragma unroll
      for (int j = 0; j < 8; ++j) qv[c * 8 + j] = b2f(v[j]);
    }
  }
  float s[3];
#pragma unroll
  for (int j3 = 0; j3 < 3; ++j3) {
    const u16x8* kp = (const u16x8*)(base + (size_t)j3 * 1536 + 512);
    float acc = 0.f;
#pragma unroll
    for (int c = 0; c < 4; ++c) {
      u16x8 v = kp[c];
#pragma unroll
      for (int j = 0; j < 8; ++j) acc += qv[c * 8 + j] * b2f(v[j]);
    }
    s[j3] = acc * 0.17677669529663687f;
  }
  float mx = fmaxf(s[0], fmaxf(s[1], s[2]));
  float e0 = __expf(s[0] - mx), e1 = __expf(s[1] - mx), e2 = __expf(s[2] - mx);
  float inv = 1.0f / (e0 + e1 + e2);
  float a0 = e0 * inv, a1 = e1 * inv, a2 = e2 * inv;
  unsigned short* op = o + (size_t)(sp * 3 + i) * 512 + h * 32;
  const u16x8* v0p = (const u16x8*)(base + 1024);
  const u16x8* v1p = (const u16x8*)(base + 1536 + 1024);
  const u16x8* v2p = (const u16x8*)(base + 3072 + 1024);
#pragma unroll
  for (int c = 0; c < 4; ++c) {
    u16x8 x0 = v0p[c], x1 = v1p[c], x2 = v2p[c];
    u16x8 ov;
#pragma unroll
    for (int j = 0; j < 8; ++j)
      ov[j] = f2b(a0 * b2f(x0[j]) + a1 * b2f(x1[j]) + a2 * b2f(x2[j]));
    *(u16x8*)(op + c * 8) = ov;
  }
}

// ---------------- mean over WS=3 ----------------
__global__ void mean3(const float* __restrict__ x, float* __restrict__ enc) {
  int i = blockIdx.x * 256 + threadIdx.x;   // float4 index, 4096*128
  if (i >= 4096 * 128) return;
  int p = i >> 7, d4 = i & 127;
  const float4* xp = (const float4*)x;
  float4 a = xp[(size_t)(p * 3 + 0) * 128 + d4];
  float4 b = xp[(size_t)(p * 3 + 1) * 128 + d4];
  float4 c = xp[(size_t)(p * 3 + 2) * 128 + d4];
  float4 o;
  o.x = (a.x + b.x + c.x) * (1.0f / 3.0f);
  o.y = (a.y + b.y + c.y) * (1.0f / 3.0f);
  o.z = (a.z + b.z + c.z) * (1.0f / 3.0f);
  o.w = (a.w + b.w + c.w) * (1.0f / 3.0f);
  ((float4*)enc)[i] = o;
}

// ---------------- cross attention, MFMA flash style ----------------
__global__ __launch_bounds__(256) void crossattn_mfma(const float* __restrict__ q,
    const unsigned short* __restrict__ Kp, const unsigned short* __restrict__ VpT,
    unsigned short* __restrict__ o) {
  __shared__ unsigned short Plds[4][2][16 * 40];
  const int sbh = blockIdx.x;
  const int side = sbh >> 9, b = (sbh >> 4) & 31, h = sbh & 15;
  const int tid = threadIdx.x;
  const int w = tid >> 6, lane = tid & 63;
  const int ql = lane & 15, g = lane >> 4;
  const int qrow = side * 2048 + b * 64 + w * 16 + ql;
  const float SC = 0.17677669529663687f;
  s16x8 qf;
  {
    const float* qp = q + (size_t)qrow * 512 + h * 32 + g * 8;
    float4 qa = ((const float4*)qp)[0];
    float4 qb4 = ((const float4*)qp)[1];
    qf[0] = (short)f2b(qa.x * SC); qf[1] = (short)f2b(qa.y * SC);
    qf[2] = (short)f2b(qa.z * SC); qf[3] = (short)f2b(qa.w * SC);
    qf[4] = (short)f2b(qb4.x * SC); qf[5] = (short)f2b(qb4.y * SC);
    qf[6] = (short)f2b(qb4.z * SC); qf[7] = (short)f2b(qb4.w * SC);
  }
  const unsigned short* kbase = Kp + ((size_t)(b * 16 + h) * 1024) * 32;
  const unsigned short* vbase = VpT + ((size_t)(b * 16 + h) * 32) * 1024;
  f32x4 oacc0 = {}, oacc1 = {};
  float m_run = -1e30f, l_part = 0.f;
  for (int kv0 = 0; kv0 < 1024; kv0 += 32) {
    const int pp = (kv0 >> 5) & 1;
    s16x8 kf0 = *(const s16x8*)(kbase + (size_t)(kv0 + ql) * 32 + g * 8);
    s16x8 kf1 = *(const s16x8*)(kbase + (size_t)(kv0 + 16 + ql) * 32 + g * 8);
    f32x4 z = {0.f, 0.f, 0.f, 0.f};
    f32x4 s0 = __builtin_amdgcn_mfma_f32_16x16x32_bf16(kf0, qf, z, 0, 0, 0);
    f32x4 s1 = __builtin_amdgcn_mfma_f32_16x16x32_bf16(kf1, qf, z, 0, 0, 0);
    float cm = fmaxf(fmaxf(fmaxf(s0[0], s0[1]), fmaxf(s0[2], s0[3])),
                     fmaxf(fmaxf(s1[0], s1[1]), fmaxf(s1[2], s1[3])));
    cm = fmaxf(cm, __shfl_xor(cm, 16));
    cm = fmaxf(cm, __shfl_xor(cm, 32));
    float m_new = fmaxf(m_run, cm);
    float corr = __expf(m_run - m_new);
    m_run = m_new;
    float p0[4], p1[4], ps = 0.f;
#pragma unroll
    for (int r = 0; r < 4; ++r) {
      p0[r] = __expf(s0[r] - m_new);
      p1[r] = __expf(s1[r] - m_new);
      ps += p0[r] + p1[r];
    }
    l_part = l_part * corr + ps;
    oacc0 *= corr; oacc1 *= corr;
    u16x4 w0, w1;
#pragma unroll
    for (int r = 0; r < 4; ++r) { w0[r] = f2b(p0[r]); w1[r] = f2b(p1[r]); }
    *(u16x4*)&Plds[w][pp][ql * 40 + g * 4] = w0;
    *(u16x4*)&Plds[w][pp][ql * 40 + 16 + g * 4] = w1;
    __syncthreads();
    s16x8 pf = *(const s16x8*)&Plds[w][pp][ql * 40 + g * 8];
    s16x8 vf0 = *(const s16x8*)(vbase + (size_t)ql * 1024 + kv0 + g * 8);
    s16x8 vf1 = *(const s16x8*)(vbase + (size_t)(16 + ql) * 1024 + kv0 + g * 8);
    oacc0 = __builtin_amdgcn_mfma_f32_16x16x32_bf16(vf0, pf, oacc0, 0, 0, 0);
    oacc1 = __builtin_amdgcn_mfma_f32_16x16x32_bf16(vf1, pf, oacc1, 0, 0, 0);
  }
  float lf = l_part;
  lf += __shfl_xor(lf, 16);
  lf += __shfl_xor(lf, 32);
  float inv = 1.0f / lf;
  unsigned short* op = o + (size_t)qrow * 512 + h * 32;
  u16x4 ov0, ov1;
#pragma unroll
  for (int r = 0; r < 4; ++r) {
    ov0[r] = f2b(oacc0[r] * inv);
    ov1[r] = f2b(oacc1[r] * inv);
  }
  *(u16x4*)(op + g * 4) = ov0;
  *(u16x4*)(op + 16 + g * 4) = ov1;
}

// ---------------- targets pass-through (output 2) ----------------
__global__ void tail_targets(const int* __restrict__ t, float* __restrict__ out) {
  int i = blockIdx.x * 256 + threadIdx.x;
  if (i < 2048) out[33554432 + i] = (float)t[i];
}

extern "C" void kernel_launch(void* const* d_in, const int* in_sizes, int n_in,
                              void* d_out, int out_size, void* d_ws, size_t ws_size,
                              hipStream_t stream) {
  const float* visual   = (const float*)d_in[0];
  const int*   targets  = (const int*)d_in[1];
  const int*   pad_p    = (const int*)d_in[2];
  const float* char_emb = (const float*)d_in[3];
  const float* ln1_g = (const float*)d_in[4];
  const float* ln1_b = (const float*)d_in[5];
  const float* in_proj_w = (const float*)d_in[6];
  const float* in_proj_b = (const float*)d_in[7];
  const float* out_w = (const float*)d_in[8];
  const float* out_b = (const float*)d_in[9];
  const float* fc1_w = (const float*)d_in[10];
  const float* fc1_b = (const float*)d_in[11];
  const float* fc2_w = (const float*)d_in[12];
  const float* fc2_b = (const float*)d_in[13];
  const float* ln2_g = (const float*)d_in[14];
  const float* ln2_b = (const float*)d_in[15];
  const float* ltok  = (const float*)d_in[16];
  const float* rtok  = (const float*)d_in[17];
  const float* q_w   = (const float*)d_in[18];
  const float* q_b   = (const float*)d_in[19];
  const float* kv_w  = (const float*)d_in[20];
  const float* kv_b  = (const float*)d_in[21];
  const float* proj_w = (const float*)d_in[22];
  const float* proj_b = (const float*)d_in[23];
  const float* lnq_g = (const float*)d_in[24];
  const float* lnq_b = (const float*)d_in[25];
  const float* lnkv_g = (const float*)d_in[26];
  const float* lnkv_b = (const float*)d_in[27];
  const float* head_w = (const float*)d_in[28];
  const float* head_b = (const float*)d_in[29];

  // workspace layout (bytes); Kp+VpT (bf16, 67MB) alias the dead encoder region
  char* ws = (char*)d_ws;
  unsigned short* W    = (unsigned short*)ws;                    // 14,680,064 B weights bf16
  float*          X    = (float*)(ws + 14680064ull);             // 25,165,824 B x fp32 12288x512
  unsigned short* KP   = (unsigned short*)(ws + 14680064ull);    // alias: 33,554,432 B Kp + 33,554,432 B VpT
  unsigned short* A1   = (unsigned short*)(ws + 39845888ull);    // 12,582,912 B bf16 12288x512
  unsigned short* B1   = (unsigned short*)(ws + 52428800ull);    // 25,165,824 B bf16 12288x1024
  unsigned short* QKV  = (unsigned short*)(ws + 77594624ull);    // 37,748,736 B bf16 12288x1536
  float*          ENC  = (float*)(ws + 115343360ull);            //  8,388,608 B fp32 4096x512
  unsigned short* VIS  = (unsigned short*)(ws + 123731968ull);   // 33,554,432 B bf16 32768x512
  float*          Q    = (float*)(ws + 157286400ull);            //  8,388,608 B fp32 4096x512
  unsigned short* OC   = (unsigned short*)(ws + 165675008ull);   //  4,194,304 B bf16 4096x512
  unsigned short* FEAT = (unsigned short*)(ws + 169869312ull);   //  4,194,304 B bf16 4096x512
  unsigned short* LNQ  = (unsigned short*)(ws + 174063616ull);   //  4,194,304 B bf16 4096x512
  unsigned short* VPT  = KP + 16777216u;

  unsigned short* Wip   = W;
  unsigned short* Wout  = W + 786432;
  unsigned short* Wfc1  = W + 1048576;
  unsigned short* Wfc2  = W + 1572864;
  unsigned short* Wq    = W + 2097152;
  unsigned short* Wkv   = W + 2359296;
  unsigned short* Wproj = W + 2883584;
  unsigned short* Whead = W + 3145728;

  auto cvt = [&](const float* s, unsigned short* d, int n) {
    cvt_f32_bf16<<<dim3((n / 4 + 255) / 256), dim3(256), 0, stream>>>(s, d, n / 4);
  };
  cvt(in_proj_w, Wip, 786432);
  cvt(out_w, Wout, 262144);
  cvt(fc1_w, Wfc1, 524288);
  cvt(fc2_w, Wfc2, 524288);
  cvt(q_w, Wq, 262144);
  cvt(kv_w, Wkv, 524288);
  cvt(proj_w, Wproj, 262144);
  cvt(head_w, Whead, 4194304);

  // ---- encoders (left+right batched, M=12288) ----
  embed_k<<<dim3(6144), dim3(256), 0, stream>>>(targets, pad_p, char_emb, ltok, rtok, X);
  ln_rows<<<dim3(3072), dim3(256), 0, stream>>>(X, ln1_g, ln1_b, A1, 12288);
  gemm128<0,0,1,0><<<dim3(12, 96), dim3(256), 0, stream>>>(A1, Wip, in_proj_b, nullptr, QKV, 12288, 1536, 512);
  winattn<<<dim3(768), dim3(256), 0, stream>>>(QKV, B1);
  gemm128<1,0,0,0><<<dim3(4, 96), dim3(256), 0, stream>>>(B1, Wout, out_b, X, X, 12288, 512, 512);
  ln_rows<<<dim3(3072), dim3(256), 0, stream>>>(X, ln2_g, ln2_b, A1, 12288);
  gemm128<0,1,1,0><<<dim3(8, 96), dim3(256), 0, stream>>>(A1, Wfc1, fc1_b, nullptr, B1, 12288, 1024, 512);
  gemm128<1,0,0,0><<<dim3(4, 96), dim3(256), 0, stream>>>(B1, Wfc2, fc2_b, X, X, 12288, 512, 1024);
  mean3<<<dim3(2048), dim3(256), 0, stream>>>(X, ENC);

  // ---- cross attention (kv shared by both sides; encoder buffers now dead) ----
  ln_rows<<<dim3(8192), dim3(256), 0, stream>>>(visual, lnkv_g, lnkv_b, VIS, 32768);
  gemm128<0,0,1,1><<<dim3(8, 256), dim3(256), 0, stream>>>(VIS, Wkv, kv_b, nullptr, KP, 32768, 1024, 512);
  ln_rows<<<dim3(1024), dim3(256), 0, stream>>>(ENC, lnq_g, lnq_b, LNQ, 4096);
  gemm128<0,0,0,0><<<dim3(4, 32), dim3(256), 0, stream>>>(LNQ, Wq, q_b, nullptr, Q, 4096, 512, 512);
  crossattn_mfma<<<dim3(1024), dim3(256), 0, stream>>>(Q, KP, VPT, OC);
  gemm128<1,0,1,0><<<dim3(4, 32), dim3(256), 0, stream>>>(OC, Wproj, proj_b, ENC, FEAT, 4096, 512, 512);

  // ---- head -> d_out (rows 0..2047 = sgm_left, 2048..4095 = sgm_right) ----
  gemm128<0,0,0,0><<<dim3(64, 32), dim3(256), 0, stream>>>(FEAT, Whead, head_b, nullptr, (float*)d_out, 4096, 8192, 512);
  tail_targets<<<dim3(8), dim3(256), 0, stream>>>(targets, (float*)d_out);
}

// Round 10
// 416.932 us; speedup vs baseline: 1.0258x; 1.0258x over previous
//
#include <hip/hip_runtime.h>
#include <hip/hip_bf16.h>
#include <cstdint>
#include <cstddef>

// SGM fused pipeline, MI355X gfx950.
// Shapes: B=32 L=64 N=1024 D=512 C=8192 WS=3 NH=16 HD=32 HID=1024
// Encoder rows M=12288 (side*6144 + pos*3 + w), cross rows 4096 (side*2048+pos).
// Residual stream X and Q are bf16 (threshold headroom ~20000x).

typedef __attribute__((ext_vector_type(8))) short s16x8;
typedef __attribute__((ext_vector_type(8))) unsigned short u16x8;
typedef __attribute__((ext_vector_type(4))) unsigned short u16x4;
typedef __attribute__((ext_vector_type(4))) float f32x4;

__device__ __forceinline__ float b2f(unsigned short u) {
  union { unsigned int i; float f; } c; c.i = ((unsigned int)u) << 16; return c.f;
}
__device__ __forceinline__ unsigned short f2b(float f) {
  union { float f; unsigned int i; } c; c.f = f;
  unsigned int x = c.i;
  return (unsigned short)((x + 0x7FFFu + ((x >> 16) & 1u)) >> 16); // RNE, no NaN in this net
}

// async global->LDS, 16B per lane; LDS dest is wave-uniform base + lane*16
#define GLOAD16(gp, lp)                                                        \
  __builtin_amdgcn_global_load_lds(                                           \
      (const __attribute__((address_space(1))) void*)(gp),                    \
      (__attribute__((address_space(3))) void*)(lp), 16, 0, 0)

// ---------------- fp32 -> bf16 convert (weights) ----------------
__global__ void cvt_f32_bf16(const float* __restrict__ s, unsigned short* __restrict__ d, int n4) {
  int i = blockIdx.x * 256 + threadIdx.x;
  if (i >= n4) return;
  float4 v = ((const float4*)s)[i];
  u16x4 o; o[0] = f2b(v.x); o[1] = f2b(v.y); o[2] = f2b(v.z); o[3] = f2b(v.w);
  *(u16x4*)(d + (size_t)i * 4) = o;
}

// ---------------- embedding + token add (bf16 out) ----------------
__global__ void embed_k(const int* __restrict__ targets, const int* __restrict__ pad_p,
                        const float* __restrict__ ce, const float* __restrict__ ltok,
                        const float* __restrict__ rtok, unsigned short* __restrict__ x) {
  int idx = blockIdx.x * 256 + threadIdx.x;   // 4-elem chunk index, 12288*128 total
  if (idx >= 12288 * 128) return;
  int row = idx >> 7, d4 = idx & 127;
  int side = row >= 6144;
  int rem = row - side * 6144;
  int pos = rem / 3, w = rem - pos * 3;
  int b = pos >> 6, l = pos & 63;
  int id;
  if (!side) { int ti = l + w - 3; id = (ti >= 0) ? targets[(b << 6) + ti] : *pad_p; }
  else       { int ti = l + w + 1; id = (ti < 64) ? targets[(b << 6) + ti] : *pad_p; }
  float4 cv = ((const float4*)ce)[(size_t)id * 128 + d4];
  float4 tv = ((const float4*)(side ? rtok : ltok))[d4];
  u16x4 o; o[0] = f2b(cv.x + tv.x); o[1] = f2b(cv.y + tv.y);
  o[2] = f2b(cv.z + tv.z); o[3] = f2b(cv.w + tv.w);
  *(u16x4*)(x + (size_t)idx * 4) = o;
}

// ---------------- LayerNorm (D=512 -> bf16 out), one wave per row; INBF: input dtype ----
template<int INBF>
__global__ __launch_bounds__(256) void ln_rows(const void* __restrict__ in,
    const float* __restrict__ g, const float* __restrict__ b,
    unsigned short* __restrict__ out, int M) {
  int row = blockIdx.x * 4 + (threadIdx.x >> 6);
  int lane = threadIdx.x & 63;
  float vv[8];
  if (INBF) {
    u16x8 v8 = *(const u16x8*)((const unsigned short*)in + (size_t)row * 512 + lane * 8);
#pragma unroll
    for (int j = 0; j < 8; ++j) vv[j] = b2f(v8[j]);
  } else {
    const float* rp = (const float*)in + (size_t)row * 512;
    float4 v0 = ((const float4*)rp)[lane * 2];
    float4 v1 = ((const float4*)rp)[lane * 2 + 1];
    vv[0] = v0.x; vv[1] = v0.y; vv[2] = v0.z; vv[3] = v0.w;
    vv[4] = v1.x; vv[5] = v1.y; vv[6] = v1.z; vv[7] = v1.w;
  }
  float s = 0.f, ss = 0.f;
#pragma unroll
  for (int j = 0; j < 8; ++j) { s += vv[j]; ss += vv[j] * vv[j]; }
#pragma unroll
  for (int o = 1; o < 64; o <<= 1) { s += __shfl_xor(s, o); ss += __shfl_xor(ss, o); }
  float mean = s * (1.0f / 512.0f);
  float var = ss * (1.0f / 512.0f) - mean * mean;
  float inv = rsqrtf(var + 1e-5f);
  int c = lane * 8;
  u16x8 o8;
#pragma unroll
  for (int j = 0; j < 8; ++j) o8[j] = f2b((vv[j] - mean) * inv * g[c + j] + b[c + j]);
  *(u16x8*)(out + (size_t)row * 512 + c) = o8;
}

// ---------------- bf16 MFMA GEMM, 128x128, BK=64 (two 32-halves), 2-phase dbuf ----------------
// Round-8 verified loop (single __syncthreads/iter, stage-in-flight across 32 MFMA),
// + adaptive block order (row-fastest when nbx>=nby) for per-XCD L2 working set,
// + bijective XCD swizzle. Row-pair XOR swizzle (conflict-free, verified =0).
// Swapped-operand MFMA -> lane holds C[row][4 consecutive cols] -> wide stores.
// RES: 0 none, 1 fp32 residual, 2 bf16 residual.
// KVT=1: writes K to Kp[b][h][n][32] (u16x4) and V^T to VpT[b][h][d][n].
template<int RES, int GELU, int OUTBF, int KVT>
__global__ __launch_bounds__(256) void gemm128(
    const unsigned short* __restrict__ A, const unsigned short* __restrict__ Bt,
    const float* __restrict__ bias, const void* __restrict__ res,
    void* __restrict__ outp, int M, int N, int K) {
  __shared__ unsigned short sA[2][8192];   // [buf][half*4096 + 128rows x 32cols swz]
  __shared__ unsigned short sB[2][8192];
  const int tid = threadIdx.x;
  const int nbx = gridDim.x, nby = gridDim.y;
  int id = blockIdx.y * nbx + blockIdx.x;
  {
    const int nwg = nbx * nby;
    if ((nwg & 7) == 0) id = (id & 7) * (nwg >> 3) + (id >> 3);
  }
  int bm, bn;
  if (nbx >= nby) { bm = (id % nby) * 128; bn = (id / nby) * 128; }   // row-fastest
  else            { bm = (id / nbx) * 128; bn = (id % nbx) * 128; }   // col-fastest
  const int wave = tid >> 6, lane = tid & 63;
  const int wr = (wave >> 1) * 64, wc = (wave & 1) * 64;
  const int lrow = lane & 15, g = lane >> 4;
  f32x4 acc[4][4] = {};
  // read-side swizzled offset within a half: rowpair slot = ((row&1)*4|g) ^ ((row>>1)&7)
  const int xoff = (((((lrow & 1) << 2) | g) ^ ((lrow >> 1) & 7)) << 3);
  const int baseA = ((wr >> 1) + (lrow >> 1)) * 64 + xoff;
  const int baseB = ((wc >> 1) + (lrow >> 1)) * 64 + xoff;
  // stage-side pre-swizzled global (row, chunk) per lane (verified layout, conflicts=0)
  const int slot8 = (tid & 7) ^ ((tid >> 3) & 7);
  const int srow = ((tid >> 3) << 1) + (slot8 >> 2);   // + i*64
  const int scol = (slot8 & 3) << 3;
  const unsigned short* gA = A + (size_t)(bm + srow) * K + scol;
  const unsigned short* gB = Bt + (size_t)(bn + srow) * K + scol;
  const int NT = K >> 6;

#define STAGE128(buf, kt)                                                      \
  { _Pragma("unroll")                                                          \
    for (int h = 0; h < 2; ++h) {                                              \
      _Pragma("unroll")                                                        \
      for (int i = 0; i < 2; ++i) {                                            \
        GLOAD16(gA + (size_t)(i * 64) * K + (kt) * 64 + h * 32,                \
                &sA[buf][h * 4096 + i * 2048 + wave * 512]);                   \
        GLOAD16(gB + (size_t)(i * 64) * K + (kt) * 64 + h * 32,                \
                &sB[buf][h * 4096 + i * 2048 + wave * 512]);                   \
      }                                                                        \
    } }

  STAGE128(0, 0);
  __syncthreads();
  int cur = 0;
  for (int kt = 0; kt < NT; ++kt) {
    // half 0 fragments
    s16x8 a0[4], b0[4];
#pragma unroll
    for (int m = 0; m < 4; ++m) a0[m] = *(const s16x8*)&sA[cur][baseA + m * 512];
#pragma unroll
    for (int n = 0; n < 4; ++n) b0[n] = *(const s16x8*)&sB[cur][baseB + n * 512];
    // stage next tile: in flight across both MFMA halves
    if (kt + 1 < NT) STAGE128(cur ^ 1, kt + 1);
    __builtin_amdgcn_s_setprio(1);
#pragma unroll
    for (int m = 0; m < 4; ++m)
#pragma unroll
      for (int n = 0; n < 4; ++n)
        acc[m][n] = __builtin_amdgcn_mfma_f32_16x16x32_bf16(b0[n], a0[m], acc[m][n], 0, 0, 0);
    __builtin_amdgcn_s_setprio(0);
    // half 1 fragments
    s16x8 a1[4], b1[4];
#pragma unroll
    for (int m = 0; m < 4; ++m) a1[m] = *(const s16x8*)&sA[cur][4096 + baseA + m * 512];
#pragma unroll
    for (int n = 0; n < 4; ++n) b1[n] = *(const s16x8*)&sB[cur][4096 + baseB + n * 512];
    __builtin_amdgcn_s_setprio(1);
#pragma unroll
    for (int m = 0; m < 4; ++m)
#pragma unroll
      for (int n = 0; n < 4; ++n)
        acc[m][n] = __builtin_amdgcn_mfma_f32_16x16x32_bf16(b1[n], a1[m], acc[m][n], 0, 0, 0);
    __builtin_amdgcn_s_setprio(0);
    __syncthreads();   // drains prefetch (overlapped a full iteration) + buffer reuse
    cur ^= 1;
  }
#undef STAGE128

  // Swapped-operand C layout: lane -> row = bm+wr+m*16+lrow, cols = bn+wc+n*16+g*4+[0..3]
  const int orow_ = bm + wr + lrow;
  const int ocol_ = bn + wc + g * 4;
#pragma unroll
  for (int m = 0; m < 4; ++m) {
    const int row = orow_ + m * 16;
#pragma unroll
    for (int n = 0; n < 4; ++n) {
      const int col = ocol_ + n * 16;
      f32x4 v = acc[m][n];
      f32x4 b4 = *(const f32x4*)(bias + col);
      v += b4;
      if (GELU) {
#pragma unroll
        for (int r = 0; r < 4; ++r)
          v[r] = 0.5f * v[r] * (1.0f + erff(v[r] * 0.70710678118654752f));
      }
      if (RES == 1) v += *(const f32x4*)((const float*)res + (size_t)row * N + col);
      if (RES == 2) {
        u16x4 r4 = *(const u16x4*)((const unsigned short*)res + (size_t)row * N + col);
#pragma unroll
        for (int r = 0; r < 4; ++r) v[r] += b2f(r4[r]);
      }
      if (KVT) {
        // row = b*1024 + n_vis ; col<512 -> K head block (contig dd), col>=512 -> V^T
        int bb = row >> 10, nn = row & 1023;
        unsigned short* Kp = (unsigned short*)outp;
        unsigned short* VpT = Kp + 16777216u;
        if (col < 512) {
          int hh = col >> 5, dd = col & 31;
          u16x4 o4;
#pragma unroll
          for (int r = 0; r < 4; ++r) o4[r] = f2b(v[r]);
          *(u16x4*)(Kp + (((size_t)(bb * 16 + hh)) * 1024 + nn) * 32 + dd) = o4;
        } else {
          int cc = col - 512, hh = cc >> 5, dd = cc & 31;
#pragma unroll
          for (int r = 0; r < 4; ++r)
            VpT[(((size_t)(bb * 16 + hh)) * 32 + dd + r) * 1024 + nn] = f2b(v[r]);
        }
      } else if (OUTBF) {
        u16x4 o4;
#pragma unroll
        for (int r = 0; r < 4; ++r) o4[r] = f2b(v[r]);
        *(u16x4*)((unsigned short*)outp + (size_t)row * N + col) = o4;
      } else {
        *(f32x4*)((float*)outp + (size_t)row * N + col) = v;
      }
    }
  }
}

// ---------------- windowed (WS=3) attention, thread per (side-pos, head, q-row) ----------------
__global__ __launch_bounds__(256) void winattn(const unsigned short* __restrict__ qkv,
                                               unsigned short* __restrict__ o) {
  int g = blockIdx.x * 256 + threadIdx.x;
  if (g >= 4096 * 48) return;
  int i = g % 3;
  int t = g / 3;
  int h = t & 15;
  int sp = t >> 4;
  const unsigned short* base = qkv + (size_t)sp * 4608 + h * 32;
  float qv[32];
  {
    const u16x8* qp = (const u16x8*)(base + (size_t)i * 1536);
#pragma unroll
    for (int c = 0; c < 4; ++c) {
      u16x8 v = qp[c];
#pragma unroll
      for (int j = 0; j < 8; ++j) qv[c * 8 + j] = b2f(v[j]);
    }
  }
  float s[3];
#pragma unroll
  for (int j3 = 0; j3 < 3; ++j3) {
    const u16x8* kp = (const u16x8*)(base + (size_t)j3 * 1536 + 512);
    float acc = 0.f;
#pragma unroll
    for (int c = 0; c < 4; ++c) {
      u16x8 v = kp[c];
#pragma unroll
      for (int j = 0; j < 8; ++j) acc += qv[c * 8 + j] * b2f(v[j]);
    }
    s[j3] = acc * 0.17677669529663687f;
  }
  float mx = fmaxf(s[0], fmaxf(s[1], s[2]));
  float e0 = __expf(s[0] - mx), e1 = __expf(s[1] - mx), e2 = __expf(s[2] - mx);
  float inv = 1.0f / (e0 + e1 + e2);
  float a0 = e0 * inv, a1 = e1 * inv, a2 = e2 * inv;
  unsigned short* op = o + (size_t)(sp * 3 + i) * 512 + h * 32;
  const u16x8* v0p = (const u16x8*)(base + 1024);
  const u16x8* v1p = (const u16x8*)(base + 1536 + 1024);
  const u16x8* v2p = (const u16x8*)(base + 3072 + 1024);
#pragma unroll
  for (int c = 0; c < 4; ++c) {
    u16x8 x0 = v0p[c], x1 = v1p[c], x2 = v2p[c];
    u16x8 ov;
#pragma unroll
    for (int j = 0; j < 8; ++j)
      ov[j] = f2b(a0 * b2f(x0[j]) + a1 * b2f(x1[j]) + a2 * b2f(x2[j]));
    *(u16x8*)(op + c * 8) = ov;
  }
}

// ---------------- mean over WS=3 (bf16 in, fp32 out) ----------------
__global__ void mean3(const unsigned short* __restrict__ x, float* __restrict__ enc) {
  int i = blockIdx.x * 256 + threadIdx.x;   // 4-elem chunk index, 4096*128
  if (i >= 4096 * 128) return;
  int p = i >> 7, d4 = i & 127;
  u16x4 a = *(const u16x4*)(x + ((size_t)(p * 3 + 0) * 512 + d4 * 4));
  u16x4 b = *(const u16x4*)(x + ((size_t)(p * 3 + 1) * 512 + d4 * 4));
  u16x4 c = *(const u16x4*)(x + ((size_t)(p * 3 + 2) * 512 + d4 * 4));
  float4 o;
  o.x = (b2f(a[0]) + b2f(b[0]) + b2f(c[0])) * (1.0f / 3.0f);
  o.y = (b2f(a[1]) + b2f(b[1]) + b2f(c[1])) * (1.0f / 3.0f);
  o.z = (b2f(a[2]) + b2f(b[2]) + b2f(c[2])) * (1.0f / 3.0f);
  o.w = (b2f(a[3]) + b2f(b[3]) + b2f(c[3])) * (1.0f / 3.0f);
  ((float4*)enc)[i] = o;
}

// ---------------- cross attention, MFMA flash style (Q bf16) ----------------
__global__ __launch_bounds__(256) void crossattn_mfma(const unsigned short* __restrict__ q,
    const unsigned short* __restrict__ Kp, const unsigned short* __restrict__ VpT,
    unsigned short* __restrict__ o) {
  __shared__ unsigned short Plds[4][2][16 * 40];
  const int sbh = blockIdx.x;
  const int side = sbh >> 9, b = (sbh >> 4) & 31, h = sbh & 15;
  const int tid = threadIdx.x;
  const int w = tid >> 6, lane = tid & 63;
  const int ql = lane & 15, g = lane >> 4;
  const int qrow = side * 2048 + b * 64 + w * 16 + ql;
  const float SC = 0.17677669529663687f;
  s16x8 qf;
  {
    u16x8 qv8 = *(const u16x8*)(q + (size_t)qrow * 512 + h * 32 + g * 8);
#pragma unroll
    for (int j = 0; j < 8; ++j) qf[j] = (short)f2b(b2f(qv8[j]) * SC);
  }
  const unsigned short* kbase = Kp + ((size_t)(b * 16 + h) * 1024) * 32;
  const unsigned short* vbase = VpT + ((size_t)(b * 16 + h) * 32) * 1024;
  f32x4 oacc0 = {}, oacc1 = {};
  float m_run = -1e30f, l_part = 0.f;
  for (int kv0 = 0; kv0 < 1024; kv0 += 32) {
    const int pp = (kv0 >> 5) & 1;
    s16x8 kf0 = *(const s16x8*)(kbase + (size_t)(kv0 + ql) * 32 + g * 8);
    s16x8 kf1 = *(const s16x8*)(kbase + (size_t)(kv0 + 16 + ql) * 32 + g * 8);
    f32x4 z = {0.f, 0.f, 0.f, 0.f};
    f32x4 s0 = __builtin_amdgcn_mfma_f32_16x16x32_bf16(kf0, qf, z, 0, 0, 0);
    f32x4 s1 = __builtin_amdgcn_mfma_f32_16x16x32_bf16(kf1, qf, z, 0, 0, 0);
    float cm = fmaxf(fmaxf(fmaxf(s0[0], s0[1]), fmaxf(s0[2], s0[3])),
                     fmaxf(fmaxf(s1[0], s1[1]), fmaxf(s1[2], s1[3])));
    cm = fmaxf(cm, __shfl_xor(cm, 16));
    cm = fmaxf(cm, __shfl_xor(cm, 32));
    float m_new = fmaxf(m_run, cm);
    float corr = __expf(m_run - m_new);
    m_run = m_new;
    float p0[4], p1[4], ps = 0.f;
#pragma unroll
    for (int r = 0; r < 4; ++r) {
      p0[r] = __expf(s0[r] - m_new);
      p1[r] = __expf(s1[r] - m_new);
      ps += p0[r] + p1[r];
    }
    l_part = l_part * corr + ps;
    oacc0 *= corr; oacc1 *= corr;
    u16x4 w0, w1;
#pragma unroll
    for (int r = 0; r < 4; ++r) { w0[r] = f2b(p0[r]); w1[r] = f2b(p1[r]); }
    *(u16x4*)&Plds[w][pp][ql * 40 + g * 4] = w0;
    *(u16x4*)&Plds[w][pp][ql * 40 + 16 + g * 4] = w1;
    __syncthreads();
    s16x8 pf = *(const s16x8*)&Plds[w][pp][ql * 40 + g * 8];
    s16x8 vf0 = *(const s16x8*)(vbase + (size_t)ql * 1024 + kv0 + g * 8);
    s16x8 vf1 = *(const s16x8*)(vbase + (size_t)(16 + ql) * 1024 + kv0 + g * 8);
    oacc0 = __builtin_amdgcn_mfma_f32_16x16x32_bf16(vf0, pf, oacc0, 0, 0, 0);
    oacc1 = __builtin_amdgcn_mfma_f32_16x16x32_bf16(vf1, pf, oacc1, 0, 0, 0);
  }
  float lf = l_part;
  lf += __shfl_xor(lf, 16);
  lf += __shfl_xor(lf, 32);
  float inv = 1.0f / lf;
  unsigned short* op = o + (size_t)qrow * 512 + h * 32;
  u16x4 ov0, ov1;
#pragma unroll
  for (int r = 0; r < 4; ++r) {
    ov0[r] = f2b(oacc0[r] * inv);
    ov1[r] = f2b(oacc1[r] * inv);
  }
  *(u16x4*)(op + g * 4) = ov0;
  *(u16x4*)(op + 16 + g * 4) = ov1;
}

// ---------------- targets pass-through (output 2) ----------------
__global__ void tail_targets(const int* __restrict__ t, float* __restrict__ out) {
  int i = blockIdx.x * 256 + threadIdx.x;
  if (i < 2048) out[33554432 + i] = (float)t[i];
}

extern "C" void kernel_launch(void* const* d_in, const int* in_sizes, int n_in,
                              void* d_out, int out_size, void* d_ws, size_t ws_size,
                              hipStream_t stream) {
  const float* visual   = (const float*)d_in[0];
  const int*   targets  = (const int*)d_in[1];
  const int*   pad_p    = (const int*)d_in[2];
  const float* char_emb = (const float*)d_in[3];
  const float* ln1_g = (const float*)d_in[4];
  const float* ln1_b = (const float*)d_in[5];
  const float* in_proj_w = (const float*)d_in[6];
  const float* in_proj_b = (const float*)d_in[7];
  const float* out_w = (const float*)d_in[8];
  const float* out_b = (const float*)d_in[9];
  const float* fc1_w = (const float*)d_in[10];
  const float* fc1_b = (const float*)d_in[11];
  const float* fc2_w = (const float*)d_in[12];
  const float* fc2_b = (const float*)d_in[13];
  const float* ln2_g = (const float*)d_in[14];
  const float* ln2_b = (const float*)d_in[15];
  const float* ltok  = (const float*)d_in[16];
  const float* rtok  = (const float*)d_in[17];
  const float* q_w   = (const float*)d_in[18];
  const float* q_b   = (const float*)d_in[19];
  const float* kv_w  = (const float*)d_in[20];
  const float* kv_b  = (const float*)d_in[21];
  const float* proj_w = (const float*)d_in[22];
  const float* proj_b = (const float*)d_in[23];
  const float* lnq_g = (const float*)d_in[24];
  const float* lnq_b = (const float*)d_in[25];
  const float* lnkv_g = (const float*)d_in[26];
  const float* lnkv_b = (const float*)d_in[27];
  const float* head_w = (const float*)d_in[28];
  const float* head_b = (const float*)d_in[29];

  // workspace layout (bytes); Kp+VpT (bf16, 67MB) alias the dead encoder region
  char* ws = (char*)d_ws;
  unsigned short* W    = (unsigned short*)ws;                    // 14,680,064 B weights bf16
  unsigned short* XB   = (unsigned short*)(ws + 14680064ull);    // 12,582,912 B x bf16 12288x512
  unsigned short* KP   = (unsigned short*)(ws + 14680064ull);    // alias: 33,554,432 B Kp + 33,554,432 B VpT
  unsigned short* A1   = (unsigned short*)(ws + 39845888ull);    // 12,582,912 B bf16 12288x512
  unsigned short* B1   = (unsigned short*)(ws + 52428800ull);    // 25,165,824 B bf16 12288x1024
  unsigned short* QKV  = (unsigned short*)(ws + 77594624ull);    // 37,748,736 B bf16 12288x1536
  float*          ENC  = (float*)(ws + 115343360ull);            //  8,388,608 B fp32 4096x512
  unsigned short* VIS  = (unsigned short*)(ws + 123731968ull);   // 33,554,432 B bf16 32768x512
  unsigned short* Q    = (unsigned short*)(ws + 157286400ull);   //  4,194,304 B bf16 4096x512
  unsigned short* OC   = (unsigned short*)(ws + 165675008ull);   //  4,194,304 B bf16 4096x512
  unsigned short* FEAT = (unsigned short*)(ws + 169869312ull);   //  4,194,304 B bf16 4096x512
  unsigned short* LNQ  = (unsigned short*)(ws + 174063616ull);   //  4,194,304 B bf16 4096x512
  unsigned short* VPT  = KP + 16777216u;

  unsigned short* Wip   = W;
  unsigned short* Wout  = W + 786432;
  unsigned short* Wfc1  = W + 1048576;
  unsigned short* Wfc2  = W + 1572864;
  unsigned short* Wq    = W + 2097152;
  unsigned short* Wkv   = W + 2359296;
  unsigned short* Wproj = W + 2883584;
  unsigned short* Whead = W + 3145728;

  auto cvt = [&](const float* s, unsigned short* d, int n) {
    cvt_f32_bf16<<<dim3((n / 4 + 255) / 256), dim3(256), 0, stream>>>(s, d, n / 4);
  };
  cvt(in_proj_w, Wip, 786432);
  cvt(out_w, Wout, 262144);
  cvt(fc1_w, Wfc1, 524288);
  cvt(fc2_w, Wfc2, 524288);
  cvt(q_w, Wq, 262144);
  cvt(kv_w, Wkv, 524288);
  cvt(proj_w, Wproj, 262144);
  cvt(head_w, Whead, 4194304);

  // ---- encoders (left+right batched, M=12288) ----
  embed_k<<<dim3(6144), dim3(256), 0, stream>>>(targets, pad_p, char_emb, ltok, rtok, XB);
  ln_rows<1><<<dim3(3072), dim3(256), 0, stream>>>(XB, ln1_g, ln1_b, A1, 12288);
  gemm128<0,0,1,0><<<dim3(12, 96), dim3(256), 0, stream>>>(A1, Wip, in_proj_b, nullptr, QKV, 12288, 1536, 512);
  winattn<<<dim3(768), dim3(256), 0, stream>>>(QKV, B1);
  gemm128<2,0,1,0><<<dim3(4, 96), dim3(256), 0, stream>>>(B1, Wout, out_b, XB, XB, 12288, 512, 512);
  ln_rows<1><<<dim3(3072), dim3(256), 0, stream>>>(XB, ln2_g, ln2_b, A1, 12288);
  gemm128<0,1,1,0><<<dim3(8, 96), dim3(256), 0, stream>>>(A1, Wfc1, fc1_b, nullptr, B1, 12288, 1024, 512);
  gemm128<2,0,1,0><<<dim3(4, 96), dim3(256), 0, stream>>>(B1, Wfc2, fc2_b, XB, XB, 12288, 512, 1024);
  mean3<<<dim3(2048), dim3(256), 0, stream>>>(XB, ENC);

  // ---- cross attention (kv shared by both sides; encoder buffers now dead) ----
  ln_rows<0><<<dim3(8192), dim3(256), 0, stream>>>(visual, lnkv_g, lnkv_b, VIS, 32768);
  gemm128<0,0,1,1><<<dim3(8, 256), dim3(256), 0, stream>>>(VIS, Wkv, kv_b, nullptr, KP, 32768, 1024, 512);
  ln_rows<0><<<dim3(1024), dim3(256), 0, stream>>>(ENC, lnq_g, lnq_b, LNQ, 4096);
  gemm128<0,0,1,0><<<dim3(4, 32), dim3(256), 0, stream>>>(LNQ, Wq, q_b, nullptr, Q, 4096, 512, 512);
  crossattn_mfma<<<dim3(1024), dim3(256), 0, stream>>>(Q, KP, VPT, OC);
  gemm128<1,0,1,0><<<dim3(4, 32), dim3(256), 0, stream>>>(OC, Wproj, proj_b, ENC, FEAT, 4096, 512, 512);

  // ---- head -> d_out (rows 0..2047 = sgm_left, 2048..4095 = sgm_right) ----
  gemm128<0,0,0,0><<<dim3(64, 32), dim3(256), 0, stream>>>(FEAT, Whead, head_b, nullptr, (float*)d_out, 4096, 8192, 512);
  tail_targets<<<dim3(8), dim3(256), 0, stream>>>(targets, (float*)d_out);
}

// Round 11
// 390.285 us; speedup vs baseline: 1.0958x; 1.0683x over previous
//
#include <hip/hip_runtime.h>
#include <hip/hip_bf16.h>
#include <cstdint>
#include <cstddef>

// SGM fused pipeline, MI355X gfx950.
// Shapes: B=32 L=64 N=1024 D=512 C=8192 WS=3 NH=16 HD=32 HID=1024
// Encoder rows M=12288 (side*6144 + pos*3 + w), cross rows 4096 (side*2048+pos).
// Residual stream X and Q are bf16 (threshold headroom ~20000x).

typedef __attribute__((ext_vector_type(8))) short s16x8;
typedef __attribute__((ext_vector_type(8))) unsigned short u16x8;
typedef __attribute__((ext_vector_type(4))) unsigned short u16x4;
typedef __attribute__((ext_vector_type(4))) float f32x4;

__device__ __forceinline__ float b2f(unsigned short u) {
  union { unsigned int i; float f; } c; c.i = ((unsigned int)u) << 16; return c.f;
}
__device__ __forceinline__ unsigned short f2b(float f) {
  union { float f; unsigned int i; } c; c.f = f;
  unsigned int x = c.i;
  return (unsigned short)((x + 0x7FFFu + ((x >> 16) & 1u)) >> 16); // RNE, no NaN in this net
}

// async global->LDS, 16B per lane; LDS dest is wave-uniform base + lane*16
#define GLOAD16(gp, lp)                                                        \
  __builtin_amdgcn_global_load_lds(                                           \
      (const __attribute__((address_space(1))) void*)(gp),                    \
      (__attribute__((address_space(3))) void*)(lp), 16, 0, 0)

// ---------------- fused fp32 -> bf16 convert for ALL weights (1 launch) ----------------
// Segments are contiguous in dst; boundaries block-aligned -> uniform branches.
__global__ void cvt_all(const float* __restrict__ s0, const float* __restrict__ s1,
                        const float* __restrict__ s2, const float* __restrict__ s3,
                        const float* __restrict__ s4, const float* __restrict__ s5,
                        const float* __restrict__ s6, const float* __restrict__ s7,
                        unsigned short* __restrict__ d) {
  int c = blockIdx.x * 256 + threadIdx.x;
  if (c >= 1835008) return;
  int e = c * 4;
  const float* sp; int off;
  if      (e <  786432) { sp = s0; off = 0; }
  else if (e < 1048576) { sp = s1; off =  786432; }
  else if (e < 1572864) { sp = s2; off = 1048576; }
  else if (e < 2097152) { sp = s3; off = 1572864; }
  else if (e < 2359296) { sp = s4; off = 2097152; }
  else if (e < 2883584) { sp = s5; off = 2359296; }
  else if (e < 3145728) { sp = s6; off = 2883584; }
  else                  { sp = s7; off = 3145728; }
  float4 v = *(const float4*)(sp + (e - off));
  u16x4 o; o[0] = f2b(v.x); o[1] = f2b(v.y); o[2] = f2b(v.z); o[3] = f2b(v.w);
  *(u16x4*)(d + e) = o;
}

// ---------------- embedding + token add (bf16 out) ----------------
__global__ void embed_k(const int* __restrict__ targets, const int* __restrict__ pad_p,
                        const float* __restrict__ ce, const float* __restrict__ ltok,
                        const float* __restrict__ rtok, unsigned short* __restrict__ x) {
  int idx = blockIdx.x * 256 + threadIdx.x;   // 4-elem chunk index, 12288*128 total
  if (idx >= 12288 * 128) return;
  int row = idx >> 7, d4 = idx & 127;
  int side = row >= 6144;
  int rem = row - side * 6144;
  int pos = rem / 3, w = rem - pos * 3;
  int b = pos >> 6, l = pos & 63;
  int id;
  if (!side) { int ti = l + w - 3; id = (ti >= 0) ? targets[(b << 6) + ti] : *pad_p; }
  else       { int ti = l + w + 1; id = (ti < 64) ? targets[(b << 6) + ti] : *pad_p; }
  float4 cv = ((const float4*)ce)[(size_t)id * 128 + d4];
  float4 tv = ((const float4*)(side ? rtok : ltok))[d4];
  u16x4 o; o[0] = f2b(cv.x + tv.x); o[1] = f2b(cv.y + tv.y);
  o[2] = f2b(cv.z + tv.z); o[3] = f2b(cv.w + tv.w);
  *(u16x4*)(x + (size_t)idx * 4) = o;
}

// ---------------- LayerNorm (D=512 -> bf16 out), one wave per row; INBF: input dtype ----
template<int INBF>
__global__ __launch_bounds__(256) void ln_rows(const void* __restrict__ in,
    const float* __restrict__ g, const float* __restrict__ b,
    unsigned short* __restrict__ out, int M) {
  int row = blockIdx.x * 4 + (threadIdx.x >> 6);
  int lane = threadIdx.x & 63;
  float vv[8];
  if (INBF) {
    u16x8 v8 = *(const u16x8*)((const unsigned short*)in + (size_t)row * 512 + lane * 8);
#pragma unroll
    for (int j = 0; j < 8; ++j) vv[j] = b2f(v8[j]);
  } else {
    const float* rp = (const float*)in + (size_t)row * 512;
    float4 v0 = ((const float4*)rp)[lane * 2];
    float4 v1 = ((const float4*)rp)[lane * 2 + 1];
    vv[0] = v0.x; vv[1] = v0.y; vv[2] = v0.z; vv[3] = v0.w;
    vv[4] = v1.x; vv[5] = v1.y; vv[6] = v1.z; vv[7] = v1.w;
  }
  float s = 0.f, ss = 0.f;
#pragma unroll
  for (int j = 0; j < 8; ++j) { s += vv[j]; ss += vv[j] * vv[j]; }
#pragma unroll
  for (int o = 1; o < 64; o <<= 1) { s += __shfl_xor(s, o); ss += __shfl_xor(ss, o); }
  float mean = s * (1.0f / 512.0f);
  float var = ss * (1.0f / 512.0f) - mean * mean;
  float inv = rsqrtf(var + 1e-5f);
  int c = lane * 8;
  u16x8 o8;
#pragma unroll
  for (int j = 0; j < 8; ++j) o8[j] = f2b((vv[j] - mean) * inv * g[c + j] + b[c + j]);
  *(u16x8*)(out + (size_t)row * 512 + c) = o8;
}

// ---------------- bf16 MFMA GEMM, 128x128, BK=64 (two 32-halves), 2-phase dbuf ----------------
// Round-8 verified structure: single __syncthreads/iter; stage(next) issued between
// half-0 ds_read and MFMA so loads fly across both MFMA halves; col-fastest block
// order (empirically faster than row-fastest despite higher FETCH — head 83 vs 93us);
// bijective XCD swizzle; row-pair XOR swizzle (bank-conflict-free, measured 0).
// Swapped-operand MFMA -> lane holds C[row][4 consecutive cols] -> wide stores.
// RES: 0 none, 1 fp32 residual, 2 bf16 residual.
// KVT=1: writes K to Kp[b][h][n][32] (u16x4) and V^T to VpT[b][h][d][n].
template<int RES, int GELU, int OUTBF, int KVT>
__global__ __launch_bounds__(256) void gemm128(
    const unsigned short* __restrict__ A, const unsigned short* __restrict__ Bt,
    const float* __restrict__ bias, const void* __restrict__ res,
    void* __restrict__ outp, int M, int N, int K) {
  __shared__ unsigned short sA[2][8192];   // [buf][half*4096 + 128rows x 32cols swz]
  __shared__ unsigned short sB[2][8192];
  const int tid = threadIdx.x;
  const int nbx = gridDim.x;
  int id = blockIdx.y * nbx + blockIdx.x;
  {
    const int nwg = nbx * gridDim.y;
    if ((nwg & 7) == 0) id = (id & 7) * (nwg >> 3) + (id >> 3);
  }
  const int bm = (id / nbx) * 128, bn = (id % nbx) * 128;   // col-fastest (round-8)
  const int wave = tid >> 6, lane = tid & 63;
  const int wr = (wave >> 1) * 64, wc = (wave & 1) * 64;
  const int lrow = lane & 15, g = lane >> 4;
  f32x4 acc[4][4] = {};
  // read-side swizzled offset within a half: rowpair slot = ((row&1)*4|g) ^ ((row>>1)&7)
  const int xoff = (((((lrow & 1) << 2) | g) ^ ((lrow >> 1) & 7)) << 3);
  const int baseA = ((wr >> 1) + (lrow >> 1)) * 64 + xoff;
  const int baseB = ((wc >> 1) + (lrow >> 1)) * 64 + xoff;
  // stage-side pre-swizzled global (row, chunk) per lane (verified layout, conflicts=0)
  const int slot8 = (tid & 7) ^ ((tid >> 3) & 7);
  const int srow = ((tid >> 3) << 1) + (slot8 >> 2);   // + i*64
  const int scol = (slot8 & 3) << 3;
  const unsigned short* gA = A + (size_t)(bm + srow) * K + scol;
  const unsigned short* gB = Bt + (size_t)(bn + srow) * K + scol;
  const int NT = K >> 6;

#define STAGE128(buf, kt)                                                      \
  { _Pragma("unroll")                                                          \
    for (int h = 0; h < 2; ++h) {                                              \
      _Pragma("unroll")                                                        \
      for (int i = 0; i < 2; ++i) {                                            \
        GLOAD16(gA + (size_t)(i * 64) * K + (kt) * 64 + h * 32,                \
                &sA[buf][h * 4096 + i * 2048 + wave * 512]);                   \
        GLOAD16(gB + (size_t)(i * 64) * K + (kt) * 64 + h * 32,                \
                &sB[buf][h * 4096 + i * 2048 + wave * 512]);                   \
      }                                                                        \
    } }

  STAGE128(0, 0);
  __syncthreads();
  int cur = 0;
  for (int kt = 0; kt < NT; ++kt) {
    // half 0 fragments
    s16x8 a0[4], b0[4];
#pragma unroll
    for (int m = 0; m < 4; ++m) a0[m] = *(const s16x8*)&sA[cur][baseA + m * 512];
#pragma unroll
    for (int n = 0; n < 4; ++n) b0[n] = *(const s16x8*)&sB[cur][baseB + n * 512];
    // stage next tile: in flight across both MFMA halves
    if (kt + 1 < NT) STAGE128(cur ^ 1, kt + 1);
    __builtin_amdgcn_s_setprio(1);
#pragma unroll
    for (int m = 0; m < 4; ++m)
#pragma unroll
      for (int n = 0; n < 4; ++n)
        acc[m][n] = __builtin_amdgcn_mfma_f32_16x16x32_bf16(b0[n], a0[m], acc[m][n], 0, 0, 0);
    __builtin_amdgcn_s_setprio(0);
    // half 1 fragments
    s16x8 a1[4], b1[4];
#pragma unroll
    for (int m = 0; m < 4; ++m) a1[m] = *(const s16x8*)&sA[cur][4096 + baseA + m * 512];
#pragma unroll
    for (int n = 0; n < 4; ++n) b1[n] = *(const s16x8*)&sB[cur][4096 + baseB + n * 512];
    __builtin_amdgcn_s_setprio(1);
#pragma unroll
    for (int m = 0; m < 4; ++m)
#pragma unroll
      for (int n = 0; n < 4; ++n)
        acc[m][n] = __builtin_amdgcn_mfma_f32_16x16x32_bf16(b1[n], a1[m], acc[m][n], 0, 0, 0);
    __builtin_amdgcn_s_setprio(0);
    __syncthreads();   // drains prefetch (overlapped a full iteration) + buffer reuse
    cur ^= 1;
  }
#undef STAGE128

  // Swapped-operand C layout: lane -> row = bm+wr+m*16+lrow, cols = bn+wc+n*16+g*4+[0..3]
  const int orow_ = bm + wr + lrow;
  const int ocol_ = bn + wc + g * 4;
#pragma unroll
  for (int m = 0; m < 4; ++m) {
    const int row = orow_ + m * 16;
#pragma unroll
    for (int n = 0; n < 4; ++n) {
      const int col = ocol_ + n * 16;
      f32x4 v = acc[m][n];
      f32x4 b4 = *(const f32x4*)(bias + col);
      v += b4;
      if (GELU) {
#pragma unroll
        for (int r = 0; r < 4; ++r)
          v[r] = 0.5f * v[r] * (1.0f + erff(v[r] * 0.70710678118654752f));
      }
      if (RES == 1) v += *(const f32x4*)((const float*)res + (size_t)row * N + col);
      if (RES == 2) {
        u16x4 r4 = *(const u16x4*)((const unsigned short*)res + (size_t)row * N + col);
#pragma unroll
        for (int r = 0; r < 4; ++r) v[r] += b2f(r4[r]);
      }
      if (KVT) {
        // row = b*1024 + n_vis ; col<512 -> K head block (contig dd), col>=512 -> V^T
        int bb = row >> 10, nn = row & 1023;
        unsigned short* Kp = (unsigned short*)outp;
        unsigned short* VpT = Kp + 16777216u;
        if (col < 512) {
          int hh = col >> 5, dd = col & 31;
          u16x4 o4;
#pragma unroll
          for (int r = 0; r < 4; ++r) o4[r] = f2b(v[r]);
          *(u16x4*)(Kp + (((size_t)(bb * 16 + hh)) * 1024 + nn) * 32 + dd) = o4;
        } else {
          int cc = col - 512, hh = cc >> 5, dd = cc & 31;
#pragma unroll
          for (int r = 0; r < 4; ++r)
            VpT[(((size_t)(bb * 16 + hh)) * 32 + dd + r) * 1024 + nn] = f2b(v[r]);
        }
      } else if (OUTBF) {
        u16x4 o4;
#pragma unroll
        for (int r = 0; r < 4; ++r) o4[r] = f2b(v[r]);
        *(u16x4*)((unsigned short*)outp + (size_t)row * N + col) = o4;
      } else {
        *(f32x4*)((float*)outp + (size_t)row * N + col) = v;
      }
    }
  }
}

// ---------------- windowed (WS=3) attention, thread per (side-pos, head, q-row) ----------------
__global__ __launch_bounds__(256) void winattn(const unsigned short* __restrict__ qkv,
                                               unsigned short* __restrict__ o) {
  int g = blockIdx.x * 256 + threadIdx.x;
  if (g >= 4096 * 48) return;
  int i = g % 3;
  int t = g / 3;
  int h = t & 15;
  int sp = t >> 4;
  const unsigned short* base = qkv + (size_t)sp * 4608 + h * 32;
  float qv[32];
  {
    const u16x8* qp = (const u16x8*)(base + (size_t)i * 1536);
#pragma unroll
    for (int c = 0; c < 4; ++c) {
      u16x8 v = qp[c];
#pragma unroll
      for (int j = 0; j < 8; ++j) qv[c * 8 + j] = b2f(v[j]);
    }
  }
  float s[3];
#pragma unroll
  for (int j3 = 0; j3 < 3; ++j3) {
    const u16x8* kp = (const u16x8*)(base + (size_t)j3 * 1536 + 512);
    float acc = 0.f;
#pragma unroll
    for (int c = 0; c < 4; ++c) {
      u16x8 v = kp[c];
#pragma unroll
      for (int j = 0; j < 8; ++j) acc += qv[c * 8 + j] * b2f(v[j]);
    }
    s[j3] = acc * 0.17677669529663687f;
  }
  float mx = fmaxf(s[0], fmaxf(s[1], s[2]));
  float e0 = __expf(s[0] - mx), e1 = __expf(s[1] - mx), e2 = __expf(s[2] - mx);
  float inv = 1.0f / (e0 + e1 + e2);
  float a0 = e0 * inv, a1 = e1 * inv, a2 = e2 * inv;
  unsigned short* op = o + (size_t)(sp * 3 + i) * 512 + h * 32;
  const u16x8* v0p = (const u16x8*)(base + 1024);
  const u16x8* v1p = (const u16x8*)(base + 1536 + 1024);
  const u16x8* v2p = (const u16x8*)(base + 3072 + 1024);
#pragma unroll
  for (int c = 0; c < 4; ++c) {
    u16x8 x0 = v0p[c], x1 = v1p[c], x2 = v2p[c];
    u16x8 ov;
#pragma unroll
    for (int j = 0; j < 8; ++j)
      ov[j] = f2b(a0 * b2f(x0[j]) + a1 * b2f(x1[j]) + a2 * b2f(x2[j]));
    *(u16x8*)(op + c * 8) = ov;
  }
}

// ---------------- mean over WS=3 (bf16 in, fp32 out) ----------------
__global__ void mean3(const unsigned short* __restrict__ x, float* __restrict__ enc) {
  int i = blockIdx.x * 256 + threadIdx.x;   // 4-elem chunk index, 4096*128
  if (i >= 4096 * 128) return;
  int p = i >> 7, d4 = i & 127;
  u16x4 a = *(const u16x4*)(x + ((size_t)(p * 3 + 0) * 512 + d4 * 4));
  u16x4 b = *(const u16x4*)(x + ((size_t)(p * 3 + 1) * 512 + d4 * 4));
  u16x4 c = *(const u16x4*)(x + ((size_t)(p * 3 + 2) * 512 + d4 * 4));
  float4 o;
  o.x = (b2f(a[0]) + b2f(b[0]) + b2f(c[0])) * (1.0f / 3.0f);
  o.y = (b2f(a[1]) + b2f(b[1]) + b2f(c[1])) * (1.0f / 3.0f);
  o.z = (b2f(a[2]) + b2f(b[2]) + b2f(c[2])) * (1.0f / 3.0f);
  o.w = (b2f(a[3]) + b2f(b[3]) + b2f(c[3])) * (1.0f / 3.0f);
  ((float4*)enc)[i] = o;
}

// ---------------- cross attention, MFMA flash style; BOTH sides per (b,h) block ----------------
// KV for (b,h) is read ONCE and shared: waves 0-3 = left side, 4-7 = right side.
__global__ __launch_bounds__(512) void crossattn_mfma(const unsigned short* __restrict__ q,
    const unsigned short* __restrict__ Kp, const unsigned short* __restrict__ VpT,
    unsigned short* __restrict__ o) {
  __shared__ unsigned short Plds[8][2][16 * 40];
  const int bh = blockIdx.x;
  const int b = bh >> 4, h = bh & 15;
  const int tid = threadIdx.x;
  const int w = tid >> 6, lane = tid & 63;
  const int side = w >> 2, wsub = w & 3;
  const int ql = lane & 15, g = lane >> 4;
  const int qrow = side * 2048 + b * 64 + wsub * 16 + ql;
  const float SC = 0.17677669529663687f;
  s16x8 qf;
  {
    u16x8 qv8 = *(const u16x8*)(q + (size_t)qrow * 512 + h * 32 + g * 8);
#pragma unroll
    for (int j = 0; j < 8; ++j) qf[j] = (short)f2b(b2f(qv8[j]) * SC);
  }
  const unsigned short* kbase = Kp + ((size_t)(b * 16 + h) * 1024) * 32;
  const unsigned short* vbase = VpT + ((size_t)(b * 16 + h) * 32) * 1024;
  f32x4 oacc0 = {}, oacc1 = {};
  float m_run = -1e30f, l_part = 0.f;
  for (int kv0 = 0; kv0 < 1024; kv0 += 32) {
    const int pp = (kv0 >> 5) & 1;
    s16x8 kf0 = *(const s16x8*)(kbase + (size_t)(kv0 + ql) * 32 + g * 8);
    s16x8 kf1 = *(const s16x8*)(kbase + (size_t)(kv0 + 16 + ql) * 32 + g * 8);
    f32x4 z = {0.f, 0.f, 0.f, 0.f};
    f32x4 s0 = __builtin_amdgcn_mfma_f32_16x16x32_bf16(kf0, qf, z, 0, 0, 0);
    f32x4 s1 = __builtin_amdgcn_mfma_f32_16x16x32_bf16(kf1, qf, z, 0, 0, 0);
    float cm = fmaxf(fmaxf(fmaxf(s0[0], s0[1]), fmaxf(s0[2], s0[3])),
                     fmaxf(fmaxf(s1[0], s1[1]), fmaxf(s1[2], s1[3])));
    cm = fmaxf(cm, __shfl_xor(cm, 16));
    cm = fmaxf(cm, __shfl_xor(cm, 32));
    float m_new = fmaxf(m_run, cm);
    float corr = __expf(m_run - m_new);
    m_run = m_new;
    float p0[4], p1[4], ps = 0.f;
#pragma unroll
    for (int r = 0; r < 4; ++r) {
      p0[r] = __expf(s0[r] - m_new);
      p1[r] = __expf(s1[r] - m_new);
      ps += p0[r] + p1[r];
    }
    l_part = l_part * corr + ps;
    oacc0 *= corr; oacc1 *= corr;
    u16x4 w0, w1;
#pragma unroll
    for (int r = 0; r < 4; ++r) { w0[r] = f2b(p0[r]); w1[r] = f2b(p1[r]); }
    *(u16x4*)&Plds[w][pp][ql * 40 + g * 4] = w0;
    *(u16x4*)&Plds[w][pp][ql * 40 + 16 + g * 4] = w1;
    __syncthreads();
    s16x8 pf = *(const s16x8*)&Plds[w][pp][ql * 40 + g * 8];
    s16x8 vf0 = *(const s16x8*)(vbase + (size_t)ql * 1024 + kv0 + g * 8);
    s16x8 vf1 = *(const s16x8*)(vbase + (size_t)(16 + ql) * 1024 + kv0 + g * 8);
    oacc0 = __builtin_amdgcn_mfma_f32_16x16x32_bf16(vf0, pf, oacc0, 0, 0, 0);
    oacc1 = __builtin_amdgcn_mfma_f32_16x16x32_bf16(vf1, pf, oacc1, 0, 0, 0);
  }
  float lf = l_part;
  lf += __shfl_xor(lf, 16);
  lf += __shfl_xor(lf, 32);
  float inv = 1.0f / lf;
  unsigned short* op = o + (size_t)qrow * 512 + h * 32;
  u16x4 ov0, ov1;
#pragma unroll
  for (int r = 0; r < 4; ++r) {
    ov0[r] = f2b(oacc0[r] * inv);
    ov1[r] = f2b(oacc1[r] * inv);
  }
  *(u16x4*)(op + g * 4) = ov0;
  *(u16x4*)(op + 16 + g * 4) = ov1;
}

// ---------------- targets pass-through (output 2) ----------------
__global__ void tail_targets(const int* __restrict__ t, float* __restrict__ out) {
  int i = blockIdx.x * 256 + threadIdx.x;
  if (i < 2048) out[33554432 + i] = (float)t[i];
}

extern "C" void kernel_launch(void* const* d_in, const int* in_sizes, int n_in,
                              void* d_out, int out_size, void* d_ws, size_t ws_size,
                              hipStream_t stream) {
  const float* visual   = (const float*)d_in[0];
  const int*   targets  = (const int*)d_in[1];
  const int*   pad_p    = (const int*)d_in[2];
  const float* char_emb = (const float*)d_in[3];
  const float* ln1_g = (const float*)d_in[4];
  const float* ln1_b = (const float*)d_in[5];
  const float* in_proj_w = (const float*)d_in[6];
  const float* in_proj_b = (const float*)d_in[7];
  const float* out_w = (const float*)d_in[8];
  const float* out_b = (const float*)d_in[9];
  const float* fc1_w = (const float*)d_in[10];
  const float* fc1_b = (const float*)d_in[11];
  const float* fc2_w = (const float*)d_in[12];
  const float* fc2_b = (const float*)d_in[13];
  const float* ln2_g = (const float*)d_in[14];
  const float* ln2_b = (const float*)d_in[15];
  const float* ltok  = (const float*)d_in[16];
  const float* rtok  = (const float*)d_in[17];
  const float* q_w   = (const float*)d_in[18];
  const float* q_b   = (const float*)d_in[19];
  const float* kv_w  = (const float*)d_in[20];
  const float* kv_b  = (const float*)d_in[21];
  const float* proj_w = (const float*)d_in[22];
  const float* proj_b = (const float*)d_in[23];
  const float* lnq_g = (const float*)d_in[24];
  const float* lnq_b = (const float*)d_in[25];
  const float* lnkv_g = (const float*)d_in[26];
  const float* lnkv_b = (const float*)d_in[27];
  const float* head_w = (const float*)d_in[28];
  const float* head_b = (const float*)d_in[29];

  // workspace layout (bytes); Kp+VpT (bf16, 67MB) alias the dead encoder region
  char* ws = (char*)d_ws;
  unsigned short* W    = (unsigned short*)ws;                    // 14,680,064 B weights bf16
  unsigned short* XB   = (unsigned short*)(ws + 14680064ull);    // 12,582,912 B x bf16 12288x512
  unsigned short* KP   = (unsigned short*)(ws + 14680064ull);    // alias: 33,554,432 B Kp + 33,554,432 B VpT
  unsigned short* A1   = (unsigned short*)(ws + 39845888ull);    // 12,582,912 B bf16 12288x512
  unsigned short* B1   = (unsigned short*)(ws + 52428800ull);    // 25,165,824 B bf16 12288x1024
  unsigned short* QKV  = (unsigned short*)(ws + 77594624ull);    // 37,748,736 B bf16 12288x1536
  float*          ENC  = (float*)(ws + 115343360ull);            //  8,388,608 B fp32 4096x512
  unsigned short* VIS  = (unsigned short*)(ws + 123731968ull);   // 33,554,432 B bf16 32768x512
  unsigned short* Q    = (unsigned short*)(ws + 157286400ull);   //  4,194,304 B bf16 4096x512
  unsigned short* OC   = (unsigned short*)(ws + 165675008ull);   //  4,194,304 B bf16 4096x512
  unsigned short* FEAT = (unsigned short*)(ws + 169869312ull);   //  4,194,304 B bf16 4096x512
  unsigned short* LNQ  = (unsigned short*)(ws + 174063616ull);   //  4,194,304 B bf16 4096x512
  unsigned short* VPT  = KP + 16777216u;

  unsigned short* Wip   = W;
  unsigned short* Wfc1  = W + 1048576;
  unsigned short* Wfc2  = W + 1572864;
  unsigned short* Wq    = W + 2097152;
  unsigned short* Wkv   = W + 2359296;
  unsigned short* Wproj = W + 2883584;
  unsigned short* Whead = W + 3145728;
  unsigned short* Wout  = W + 786432;

  // one fused convert for all 8 weight matrices (1,835,008 float4 chunks)
  cvt_all<<<dim3(7168), dim3(256), 0, stream>>>(in_proj_w, out_w, fc1_w, fc2_w,
                                                q_w, kv_w, proj_w, head_w, W);

  // ---- encoders (left+right batched, M=12288) ----
  embed_k<<<dim3(6144), dim3(256), 0, stream>>>(targets, pad_p, char_emb, ltok, rtok, XB);
  ln_rows<1><<<dim3(3072), dim3(256), 0, stream>>>(XB, ln1_g, ln1_b, A1, 12288);
  gemm128<0,0,1,0><<<dim3(12, 96), dim3(256), 0, stream>>>(A1, Wip, in_proj_b, nullptr, QKV, 12288, 1536, 512);
  winattn<<<dim3(768), dim3(256), 0, stream>>>(QKV, B1);
  gemm128<2,0,1,0><<<dim3(4, 96), dim3(256), 0, stream>>>(B1, Wout, out_b, XB, XB, 12288, 512, 512);
  ln_rows<1><<<dim3(3072), dim3(256), 0, stream>>>(XB, ln2_g, ln2_b, A1, 12288);
  gemm128<0,1,1,0><<<dim3(8, 96), dim3(256), 0, stream>>>(A1, Wfc1, fc1_b, nullptr, B1, 12288, 1024, 512);
  gemm128<2,0,1,0><<<dim3(4, 96), dim3(256), 0, stream>>>(B1, Wfc2, fc2_b, XB, XB, 12288, 512, 1024);
  mean3<<<dim3(2048), dim3(256), 0, stream>>>(XB, ENC);

  // ---- cross attention (kv shared by both sides; encoder buffers now dead) ----
  ln_rows<0><<<dim3(8192), dim3(256), 0, stream>>>(visual, lnkv_g, lnkv_b, VIS, 32768);
  gemm128<0,0,1,1><<<dim3(8, 256), dim3(256), 0, stream>>>(VIS, Wkv, kv_b, nullptr, KP, 32768, 1024, 512);
  ln_rows<0><<<dim3(1024), dim3(256), 0, stream>>>(ENC, lnq_g, lnq_b, LNQ, 4096);
  gemm128<0,0,1,0><<<dim3(4, 32), dim3(256), 0, stream>>>(LNQ, Wq, q_b, nullptr, Q, 4096, 512, 512);
  crossattn_mfma<<<dim3(512), dim3(512), 0, stream>>>(Q, KP, VPT, OC);
  gemm128<1,0,1,0><<<dim3(4, 32), dim3(256), 0, stream>>>(OC, Wproj, proj_b, ENC, FEAT, 4096, 512, 512);

  // ---- head -> d_out (rows 0..2047 = sgm_left, 2048..4095 = sgm_right) ----
  gemm128<0,0,0,0><<<dim3(64, 32), dim3(256), 0, stream>>>(FEAT, Whead, head_b, nullptr, (float*)d_out, 4096, 8192, 512);
  tail_targets<<<dim3(8), dim3(256), 0, stream>>>(targets, (float*)d_out);
}